// Round 12
// baseline (489.159 us; speedup 1.0000x reference)
//
#include <hip/hip_runtime.h>
#include <hip/hip_cooperative_groups.h>
#include <math.h>

#define FIN 128
#define FOUT 64
#define MAXDEG 64
#define BKT_SHIFT 7           // 128 dsts per bucket (write-amp-free binA staging)
#define BKT_CAP 2560          // mean 2048, +11 sigma

namespace cg = cooperative_groups;

// ---------------- helpers ----------------

__device__ __forceinline__ float4 f4add(float4 a, float4 b) {
  return make_float4(a.x + b.x, a.y + b.y, a.z + b.z, a.w + b.w);
}
__device__ __forceinline__ float4 f4fma(float c, float4 v, float4 a) {
  return make_float4(fmaf(c, v.x, a.x), fmaf(c, v.y, a.y),
                     fmaf(c, v.z, a.z), fmaf(c, v.w, a.w));
}
__device__ __forceinline__ float red16(float v) {
  v += __shfl_xor(v, 1, 64);
  v += __shfl_xor(v, 2, 64);
  v += __shfl_xor(v, 4, 64);
  v += __shfl_xor(v, 8, 64);
  return v;
}

// logmap0 row factor: artanh(clip(n))/max(n,1e-15), c=1
__device__ __forceinline__ float row_scale(float ss) {
  float n  = sqrtf(ss);
  float nc = fmaxf(n, 1e-15f);
  float t  = fminf(nc, 1.0f - 1e-7f);
  float at = 0.5f * (log1pf(t) - log1pf(-t));
  return at / nc;
}

__device__ __forceinline__ float leaky(float v) {
  return (v >= 0.f) ? v : 0.01f * v;
}

// bf16 pack (RNE) / unpack uint2 -> 4 floats
__device__ __forceinline__ unsigned int bf16rne(float x) {
  unsigned int b = __float_as_uint(x);
  b += 0x7FFFu + ((b >> 16) & 1u);
  return b >> 16;
}
__device__ __forceinline__ float4 bf4(uint2 v) {
  return make_float4(__uint_as_float(v.x << 16),
                     __uint_as_float(v.x & 0xFFFF0000u),
                     __uint_as_float(v.y << 16),
                     __uint_as_float(v.y & 0xFFFF0000u));
}

// ---------------- kernel 1: [gemm 64-node tiles, single phase] U [binA] -----
// f32 vector GEMM (round-2 proven): the x->u->p chain feeds a hard threshold
// (p > 0.48), so the GEMM must stay f32-grade — f16/bf16 MFMA flips gates.
// Two-phase binning at shift 7 (round-9: shift 6 cost +12MB binA write amp).
__global__ __launch_bounds__(256) void k_main(const float* __restrict__ x,
                                              const float* __restrict__ Wup,
                                              const float* __restrict__ Wpl,
                                              const float* __restrict__ Wlw,
                                              float* __restrict__ u,
                                              float* __restrict__ scl4,
                                              const int* __restrict__ ei, int E,
                                              int nb, int* __restrict__ bcnt,
                                              int2* __restrict__ stg,
                                              int N, int gemmBlocks) {
  __shared__ float buf[8192];      // xs: 128k x 64n (32KB) / us[n*67+f] (17KB); binA: hist+base
  __shared__ float wls[256];
  __shared__ float ps[256];
  __shared__ float scl[64];

  int t = threadIdx.x;

  if (blockIdx.x >= gemmBlocks) {
    // ================= binA branch =================
    int* hist = (int*)buf;
    int* base = hist + nb;
    int bb = blockIdx.x - gemmBlocks;
    for (int h = t; h < nb; h += 256) hist[h] = 0;
    __syncthreads();
    int e0 = bb * 4096 + t * 16;
    int sv[16], dv[16];
#pragma unroll
    for (int j = 0; j < 16; j += 4) {
      int e = e0 + j;
      if (e + 3 < E) {
        int4 s4 = *(const int4*)(ei + e);
        int4 d4 = *(const int4*)(ei + E + e);
        sv[j] = s4.x; sv[j+1] = s4.y; sv[j+2] = s4.z; sv[j+3] = s4.w;
        dv[j] = d4.x; dv[j+1] = d4.y; dv[j+2] = d4.z; dv[j+3] = d4.w;
      } else {
        for (int q = 0; q < 4; ++q) {
          int ee = e + q;
          sv[j+q] = (ee < E) ? ei[ee] : -1;
          dv[j+q] = (ee < E) ? ei[E + ee] : -1;
        }
      }
    }
#pragma unroll
    for (int j = 0; j < 16; ++j)
      if (dv[j] >= 0) atomicAdd(&hist[dv[j] >> BKT_SHIFT], 1);
    __syncthreads();
    for (int h = t; h < nb; h += 256)
      base[h] = hist[h] ? atomicAdd(&bcnt[h], hist[h]) : 0;
    __syncthreads();
    for (int h = t; h < nb; h += 256) hist[h] = 0;
    __syncthreads();
#pragma unroll
    for (int j = 0; j < 16; ++j) {
      if (dv[j] < 0) continue;
      int b = dv[j] >> BKT_SHIFT;
      int p = base[b] + atomicAdd(&hist[b], 1);
      if (p < BKT_CAP) stg[(size_t)b * BKT_CAP + p] = make_int2(sv[j], dv[j]);
    }
    return;
  }

  // ================= gemm branch: 64 nodes/block, single K phase ==========
  int n0 = blockIdx.x * 64;
  {
    int proj = t >> 6, f = t & 63;
    float wv = (proj == 0) ? Wpl[f * 2]
             : (proj == 1) ? Wpl[f * 2 + 1]
             : (proj == 2) ? Wlw[f] : Wlw[64 + f];
    wls[t] = wv;
  }

  // stage: thread t owns node n = t&63, k-quarter kq = t>>6 (8 float4)
  {
    int n  = t & 63;
    int kq = t >> 6;
    int gn = n0 + n;
    bool ok = gn < N;
    const float4* xr = (const float4*)(x + (size_t)gn * FIN);
    float ssum = 0.f;
    float4 r0[8];
#pragma unroll
    for (int m = 0; m < 8; ++m)
      r0[m] = ok ? xr[kq * 8 + m] : make_float4(0.f, 0.f, 0.f, 0.f);
#pragma unroll
    for (int m = 0; m < 8; ++m) {
      float4 v = r0[m];
      ssum = fmaf(v.x, v.x, fmaf(v.y, v.y, fmaf(v.z, v.z, fmaf(v.w, v.w, ssum))));
      int kf = kq * 32 + m * 4;
      buf[(kf + 0) * 64 + n] = v.x;
      buf[(kf + 1) * 64 + n] = v.y;
      buf[(kf + 2) * 64 + n] = v.z;
      buf[(kf + 3) * 64 + n] = v.w;
    }
    ps[t] = ssum;
  }
  __syncthreads();                 // xs + ps ready
  if (t < 64) scl[t] = row_scale(ps[t] + ps[t + 64] + ps[t + 128] + ps[t + 192]);

  // gemm: wave w owns cols [w*16, w*16+16); lane: j = lane&3 (4 cols),
  // i = lane>>2 (4 nodes). Quad-broadcast x read, 64B-coalesced u store.
  int wave = t >> 6, lane = t & 63;
  int j = lane & 3, i = lane >> 2;
  const float* xp = buf + i * 4;
  const float* wg = Wup + wave * 16 + j * 4;
  float4 a0 = make_float4(0,0,0,0), a1 = a0, a2 = a0, a3 = a0;
#pragma unroll 8
  for (int k = 0; k < FIN; ++k) {
    float4 xv = *(const float4*)(xp + k * 64);
    float4 wv = *(const float4*)(wg + k * 64);
    a0 = f4fma(xv.x, wv, a0);
    a1 = f4fma(xv.y, wv, a1);
    a2 = f4fma(xv.z, wv, a2);
    a3 = f4fma(xv.w, wv, a3);
  }
  __syncthreads();                 // xs dead, scl visible; buf -> us[n*67+f]

  int fbase = wave * 16 + j * 4;
#pragma unroll
  for (int r = 0; r < 4; ++r) {
    float4 acc = (r == 0) ? a0 : (r == 1) ? a1 : (r == 2) ? a2 : a3;
    int nn = i * 4 + r;
    int gnn = n0 + nn;
    float sc = scl[nn];
    float4 o = make_float4(leaky(sc * acc.x), leaky(sc * acc.y),
                           leaky(sc * acc.z), leaky(sc * acc.w));
    if (gnn < N) *(float4*)(u + (size_t)gnn * FOUT + fbase) = o;
    buf[nn * 67 + fbase]     = o.x;    // stride 67: read pass conflict-free
    buf[nn * 67 + fbase + 1] = o.y;
    buf[nn * 67 + fbase + 2] = o.z;
    buf[nn * 67 + fbase + 3] = o.w;
  }
  __syncthreads();

  {
    int proj = t >> 6;
    const float* wc = wls + proj * 64;
    int nn = t & 63;
    int gnn = n0 + nn;
    const float* ur = buf + nn * 67;   // (3n+f)%32: conflict-free across lanes
    float acc = 0.f;
#pragma unroll 8
    for (int f = 0; f < 64; ++f) acc = fmaf(ur[f], wc[f], acc);
    if (gnn < N) scl4[(size_t)gnn * 4 + proj] = acc;
  }
}

// ---------------- kernel 2: cooperative fused tail ---------------------------
// Phase 1: bucket placement into LDS (binB) + gate (aggA) -> gs global.
// grid.sync
// Phase 2: weight + in-LDS compaction (k_wgt) -> uw global (overlays stg,
//          which is dead after phase 1).
// grid.sync
// Phase 3: compacted uw gather + epilogue (k_agg3) -> out.
// The adjacency (slds) persists in LDS across phases: global slots/deg/scnt/tp
// arrays deleted. 782 blocks x (34.8KB LDS, <=128 VGPR) -> 4 blocks/CU
// co-resident capacity 1024 >= 782.
__global__ __launch_bounds__(256, 4) void k_tail(const int2* __restrict__ stg,
                                                 const int* __restrict__ bcnt,
                                                 const float4* __restrict__ scl4,
                                                 const float* __restrict__ u,
                                                 float2* __restrict__ gs,
                                                 unsigned int* __restrict__ uw,
                                                 float* __restrict__ out, int N) {
  __shared__ int   slds[128 * MAXDEG];  // 32KB adjacency (then compacted in ph2)
  __shared__ int   cur[128];            // degree
  __shared__ int   scntl[128];          // selected count (ph2 -> ph3)
  __shared__ float tps[128];            // tp (ph1 -> ph2)
  __shared__ float sell[128];           // sel flag (ph1 -> ph2)
  cg::grid_group grid = cg::this_grid();

  int b = blockIdx.x, t = threadIdx.x;
  int dbase = b << BKT_SHIFT;
  int grp = t >> 4, l16 = t & 15;
  int lane = t & 63, gw = lane >> 4;    // group index within wave (ballots)

  // ================= phase 1a: placement =================
  if (t < 128) cur[t] = 0;
  __syncthreads();
  int cnt = min(bcnt[b], BKT_CAP);
  const int2* sp = stg + (size_t)b * BKT_CAP;
  for (int i = t; i < cnt; i += 256) {
    int2 e = sp[i];
    int dl = e.y - dbase;
    int p = atomicAdd(&cur[dl], 1);
    if (p < MAXDEG) slds[dl * MAXDEG + p] = e.x;
  }
  __syncthreads();                 // slds + cur complete

  // ================= phase 1b: gate (16 lanes/node, 8 reps) ==============
#pragma unroll
  for (int rep = 0; rep < 8; ++rep) {
    int nl = rep * 16 + grp;
    int i  = dbase + nl;
    bool act = (i < N);
    int d = act ? min(cur[nl], MAXDEG) : 0;
    float ax = 0.f, ay = 0.f, aw = 0.f;
#pragma unroll
    for (int q = 0; q < 4; ++q) {
      int k = l16 + q * 16;
      if (k < d) {
        int s = slds[nl * MAXDEG + k];
        float4 gg = scl4[s];
        ax += gg.x; ay += gg.y; aw += gg.w;
      }
    }
    ax = red16(ax); ay = red16(ay); aw = red16(aw);
    if (act && l16 == 0) {
      float r0 = fmaxf(ax, 0.f), r1 = fmaxf(ay, 0.f);
      float m  = fmaxf(r0, r1);
      float e0 = expf(r0 - m), e1 = expf(r1 - m);
      float p  = e1 / (e0 + e1);
      float sel = (p > 0.48f) ? 1.f : 0.f;
      float4 own = scl4[i];
      gs[i] = make_float2(sel, sel * own.z);  // {selF, selF*q1}
      tps[nl]  = aw;
      sell[nl] = sel;
    }
  }
  __threadfence();
  grid.sync();                     // gs visible device-wide; stg dead

  // ================= phase 2: weight + in-LDS compaction + uw ============
  if (b == 0 && t < 32) uw[(size_t)N * 32 + t] = 0u;   // sentinel row N
  for (int rep = 0; rep < 8; ++rep) {
    int nl = rep * 16 + grp;
    int i  = dbase + nl;
    bool act = (i < N);
    int d = act ? min(cur[nl], MAXDEG) : 0;
    int sv[4]; bool f[4];
    float a = 0.f;
#pragma unroll
    for (int q = 0; q < 4; ++q) {
      int k = l16 + q * 16;
      bool valid = k < d;
      int s = 0;
      if (valid) s = slds[nl * MAXDEG + k];
      sv[q] = s;
      float2 gv = make_float2(0.f, 0.f);
      if (valid) gv = gs[s];
      f[q] = valid && (gv.x != 0.f);
      a += gv.y;
    }
    a = red16(a);                     // all 16 lanes hold sum of sel*q1
    unsigned long long m0 = __ballot(f[0]);
    unsigned long long m1 = __ballot(f[1]);
    unsigned long long m2 = __ballot(f[2]);
    unsigned long long m3 = __ballot(f[3]);
    int sh = gw * 16;
    unsigned gm0 = (unsigned)(m0 >> sh) & 0xFFFFu;
    unsigned gm1 = (unsigned)(m1 >> sh) & 0xFFFFu;
    unsigned gm2 = (unsigned)(m2 >> sh) & 0xFFFFu;
    unsigned gm3 = (unsigned)(m3 >> sh) & 0xFFFFu;
    int c0 = __popc(gm0), c1 = __popc(gm1), c2 = __popc(gm2);
    unsigned lm = (1u << l16) - 1u;
    int r0 = __popc(gm0 & lm);
    int r1 = c0 + __popc(gm1 & lm);
    int r2 = c0 + c1 + __popc(gm2 & lm);
    int r3 = c0 + c1 + c2 + __popc(gm3 & lm);
    // reads of the row (sv[]) completed above in lockstep; in-place compact
    if (f[0]) slds[nl * MAXDEG + r0] = sv[0];
    if (f[1]) slds[nl * MAXDEG + r1] = sv[1];
    if (f[2]) slds[nl * MAXDEG + r2] = sv[2];
    if (f[3]) slds[nl * MAXDEG + r3] = sv[3];
    if (act && l16 == 0) scntl[nl] = c0 + c1 + c2 + __popc(gm3);
    if (act && sell[nl] != 0.f) {     // group-uniform: selected node
      float sig = 1.f / (1.f + expf(-(tps[nl] + a)));
      float4 uv = ((const float4*)(u + (size_t)i * 64))[l16];
      unsigned int b0 = bf16rne(sig * uv.x), b1 = bf16rne(sig * uv.y);
      unsigned int b2 = bf16rne(sig * uv.z), b3 = bf16rne(sig * uv.w);
      ((uint2*)(uw + (size_t)i * 32))[l16] =
          make_uint2(b0 | (b1 << 16), b2 | (b3 << 16));
    }
  }
  __threadfence();
  grid.sync();                     // uw visible device-wide

  // ================= phase 3: compacted gather + epilogue ================
  const uint2* uw2 = (const uint2*)uw;
  for (int rep = 0; rep < 8; ++rep) {
    int nl = rep * 16 + grp;
    int i  = dbase + nl;
    bool act = (i < N);
    int sc = act ? scntl[nl] : 0;
    float4 acc = make_float4(0.f, 0.f, 0.f, 0.f);
    for (int r = 0; r < sc; r += 4) {
#pragma unroll
      for (int j = 0; j < 4; ++j) {
        int idx = r + j;
        int s = (idx < sc) ? slds[nl * MAXDEG + idx] : N;  // row N is zeroed
        uint2 w = uw2[(size_t)s * 16 + l16];
        acc = f4add(acc, bf4(w));
      }
    }
    if (!act) continue;
    float4 uv = ((const float4*)(u + (size_t)i * 64))[l16];
    float4 ov = make_float4(uv.x + fmaxf(acc.x, 0.f), uv.y + fmaxf(acc.y, 0.f),
                            uv.z + fmaxf(acc.z, 0.f), uv.w + fmaxf(acc.w, 0.f));
    float ssp = ov.x * ov.x + ov.y * ov.y + ov.z * ov.z + ov.w * ov.w;
    float ss  = red16(ssp);
    float nc  = fmaxf(sqrtf(ss), 1e-15f);
    float th  = tanhf(nc);
    float fac = th / nc;
    float4 r4 = make_float4(ov.x * fac, ov.y * fac, ov.z * fac, ov.w * fac);
    float n2 = fmaxf(th, 1e-15f);
    float maxn = 1.0f - 4e-3f;
    float sc2 = (n2 > maxn) ? (maxn / n2) : 1.0f;
    float4 res = make_float4(r4.x * sc2, r4.y * sc2, r4.z * sc2, r4.w * sc2);
    ((float4*)(out + (size_t)i * 64))[l16] = res;
  }
}

// ---------------- launch ----------------
extern "C" void kernel_launch(void* const* d_in, const int* in_sizes, int n_in,
                              void* d_out, int out_size, void* d_ws, size_t ws_size,
                              hipStream_t stream) {
  const float* x   = (const float*)d_in[0];
  const int*   ei  = (const int*)d_in[1];
  const float* Wup = (const float*)d_in[2];
  const float* Wpl = (const float*)d_in[3];
  const float* Wlw = (const float*)d_in[4];
  float* out = (float*)d_out;

  int N = in_sizes[0] / FIN;     // 100000
  int E = in_sizes[1] / 2;       // 1600000
  int nb = (N + (1 << BKT_SHIFT) - 1) >> BKT_SHIFT;   // 782 buckets

  char* ws = (char*)d_ws;
  float* u     = (float*)ws;                            // 25.6 MB
  char*  regB  = (char*)(u + (size_t)N * 64);           // union: stg | uw
  size_t regB_sz = (size_t)nb * BKT_CAP * sizeof(int2); // 16.0 MB
  int2*  stg   = (int2*)regB;               // lifetime: k_main(binA) -> k_tail ph1
  unsigned int* uwp = (unsigned int*)regB;  // lifetime: k_tail ph2 -> ph3
  float* scl4  = (float*)(regB + regB_sz);              // 1.6 MB
  float2* gs   = (float2*)(scl4 + (size_t)N * 4);       // 0.8 MB
  int*   bcnt  = (int*)(gs + N);                        // tiny

  (void)hipMemsetAsync(bcnt, 0, nb * sizeof(int), stream);

  int gemmBlocks = (N + 63) / 64;                 // 1563
  int binABlocks = (E + 4095) / 4096;             // 391
  k_main<<<gemmBlocks + binABlocks, 256, 0, stream>>>(
      x, Wup, Wpl, Wlw, u, scl4, ei, E, nb, bcnt, stg, N, gemmBlocks);

  const int2*   stgc  = stg;
  const int*    bcntc = bcnt;
  const float4* scl4c = (const float4*)scl4;
  const float*  uc    = u;
  void* kargs[] = {(void*)&stgc, (void*)&bcntc, (void*)&scl4c, (void*)&uc,
                   (void*)&gs, (void*)&uwp, (void*)&out, (void*)&N};
  (void)hipLaunchCooperativeKernel((const void*)k_tail, dim3(nb), dim3(256),
                                   kargs, 0, stream);
}

// Round 13
// 196.467 us; speedup vs baseline: 2.4898x; 2.4898x over previous
//
#include <hip/hip_runtime.h>
#include <math.h>

#define FIN 128
#define FOUT 64
#define MAXDEG 64
#define BKT_SHIFT 7           // 128 dsts per bucket (write-amp-free binA staging)
#define BKT_CAP 2560          // mean 2048, +11 sigma

// ---------------- helpers ----------------

__device__ __forceinline__ float4 f4add(float4 a, float4 b) {
  return make_float4(a.x + b.x, a.y + b.y, a.z + b.z, a.w + b.w);
}
__device__ __forceinline__ float4 f4fma(float c, float4 v, float4 a) {
  return make_float4(fmaf(c, v.x, a.x), fmaf(c, v.y, a.y),
                     fmaf(c, v.z, a.z), fmaf(c, v.w, a.w));
}
__device__ __forceinline__ float red16(float v) {
  v += __shfl_xor(v, 1, 64);
  v += __shfl_xor(v, 2, 64);
  v += __shfl_xor(v, 4, 64);
  v += __shfl_xor(v, 8, 64);
  return v;
}

// logmap0 row factor: artanh(clip(n))/max(n,1e-15), c=1
__device__ __forceinline__ float row_scale(float ss) {
  float n  = sqrtf(ss);
  float nc = fmaxf(n, 1e-15f);
  float t  = fminf(nc, 1.0f - 1e-7f);
  float at = 0.5f * (log1pf(t) - log1pf(-t));
  return at / nc;
}

__device__ __forceinline__ float leaky(float v) {
  return (v >= 0.f) ? v : 0.01f * v;
}

// bf16 pack (RNE) / unpack uint2 -> 4 floats
__device__ __forceinline__ unsigned int bf16rne(float x) {
  unsigned int b = __float_as_uint(x);
  b += 0x7FFFu + ((b >> 16) & 1u);
  return b >> 16;
}
__device__ __forceinline__ float4 bf4(uint2 v) {
  return make_float4(__uint_as_float(v.x << 16),
                     __uint_as_float(v.x & 0xFFFF0000u),
                     __uint_as_float(v.y << 16),
                     __uint_as_float(v.y & 0xFFFF0000u));
}

// ---------------- kernel 1: [gemm 64-node tiles, single phase] U [binA] -----
// f32 vector GEMM (round-2 proven): the x->u->p chain feeds a hard threshold
// (p > 0.48), so the GEMM must stay f32-grade — f16/bf16 MFMA flips gates.
// Two-phase binning at shift 7 (round-9: shift 6 cost +12MB binA write amp).
__global__ __launch_bounds__(256) void k_main(const float* __restrict__ x,
                                              const float* __restrict__ Wup,
                                              const float* __restrict__ Wpl,
                                              const float* __restrict__ Wlw,
                                              float* __restrict__ u,
                                              float* __restrict__ scl4,
                                              const int* __restrict__ ei, int E,
                                              int nb, int* __restrict__ bcnt,
                                              int2* __restrict__ stg,
                                              int N, int gemmBlocks) {
  __shared__ float buf[8192];      // xs: 128k x 64n (32KB) / us[n*67+f] (17KB); binA: hist+base
  __shared__ float wls[256];
  __shared__ float ps[256];
  __shared__ float scl[64];

  int t = threadIdx.x;

  if (blockIdx.x >= gemmBlocks) {
    // ================= binA branch =================
    int* hist = (int*)buf;
    int* base = hist + nb;
    int bb = blockIdx.x - gemmBlocks;
    for (int h = t; h < nb; h += 256) hist[h] = 0;
    __syncthreads();
    int e0 = bb * 4096 + t * 16;
    int sv[16], dv[16];
#pragma unroll
    for (int j = 0; j < 16; j += 4) {
      int e = e0 + j;
      if (e + 3 < E) {
        int4 s4 = *(const int4*)(ei + e);
        int4 d4 = *(const int4*)(ei + E + e);
        sv[j] = s4.x; sv[j+1] = s4.y; sv[j+2] = s4.z; sv[j+3] = s4.w;
        dv[j] = d4.x; dv[j+1] = d4.y; dv[j+2] = d4.z; dv[j+3] = d4.w;
      } else {
        for (int q = 0; q < 4; ++q) {
          int ee = e + q;
          sv[j+q] = (ee < E) ? ei[ee] : -1;
          dv[j+q] = (ee < E) ? ei[E + ee] : -1;
        }
      }
    }
#pragma unroll
    for (int j = 0; j < 16; ++j)
      if (dv[j] >= 0) atomicAdd(&hist[dv[j] >> BKT_SHIFT], 1);
    __syncthreads();
    for (int h = t; h < nb; h += 256)
      base[h] = hist[h] ? atomicAdd(&bcnt[h], hist[h]) : 0;
    __syncthreads();
    for (int h = t; h < nb; h += 256) hist[h] = 0;
    __syncthreads();
#pragma unroll
    for (int j = 0; j < 16; ++j) {
      if (dv[j] < 0) continue;
      int b = dv[j] >> BKT_SHIFT;
      int p = base[b] + atomicAdd(&hist[b], 1);
      if (p < BKT_CAP) stg[(size_t)b * BKT_CAP + p] = make_int2(sv[j], dv[j]);
    }
    return;
  }

  // ================= gemm branch: 64 nodes/block, single K phase ==========
  int n0 = blockIdx.x * 64;
  {
    int proj = t >> 6, f = t & 63;
    float wv = (proj == 0) ? Wpl[f * 2]
             : (proj == 1) ? Wpl[f * 2 + 1]
             : (proj == 2) ? Wlw[f] : Wlw[64 + f];
    wls[t] = wv;
  }

  // stage: thread t owns node n = t&63, k-quarter kq = t>>6 (8 float4)
  {
    int n  = t & 63;
    int kq = t >> 6;
    int gn = n0 + n;
    bool ok = gn < N;
    const float4* xr = (const float4*)(x + (size_t)gn * FIN);
    float ssum = 0.f;
    float4 r0[8];
#pragma unroll
    for (int m = 0; m < 8; ++m)
      r0[m] = ok ? xr[kq * 8 + m] : make_float4(0.f, 0.f, 0.f, 0.f);
#pragma unroll
    for (int m = 0; m < 8; ++m) {
      float4 v = r0[m];
      ssum = fmaf(v.x, v.x, fmaf(v.y, v.y, fmaf(v.z, v.z, fmaf(v.w, v.w, ssum))));
      int kf = kq * 32 + m * 4;
      buf[(kf + 0) * 64 + n] = v.x;
      buf[(kf + 1) * 64 + n] = v.y;
      buf[(kf + 2) * 64 + n] = v.z;
      buf[(kf + 3) * 64 + n] = v.w;
    }
    ps[t] = ssum;
  }
  __syncthreads();                 // xs + ps ready
  if (t < 64) scl[t] = row_scale(ps[t] + ps[t + 64] + ps[t + 128] + ps[t + 192]);

  // gemm: wave w owns cols [w*16, w*16+16); lane: j = lane&3 (4 cols),
  // i = lane>>2 (4 nodes). Quad-broadcast x read, 64B-coalesced u store.
  int wave = t >> 6, lane = t & 63;
  int j = lane & 3, i = lane >> 2;
  const float* xp = buf + i * 4;
  const float* wg = Wup + wave * 16 + j * 4;
  float4 a0 = make_float4(0,0,0,0), a1 = a0, a2 = a0, a3 = a0;
#pragma unroll 8
  for (int k = 0; k < FIN; ++k) {
    float4 xv = *(const float4*)(xp + k * 64);
    float4 wv = *(const float4*)(wg + k * 64);
    a0 = f4fma(xv.x, wv, a0);
    a1 = f4fma(xv.y, wv, a1);
    a2 = f4fma(xv.z, wv, a2);
    a3 = f4fma(xv.w, wv, a3);
  }
  __syncthreads();                 // xs dead, scl visible; buf -> us[n*67+f]

  int fbase = wave * 16 + j * 4;
#pragma unroll
  for (int r = 0; r < 4; ++r) {
    float4 acc = (r == 0) ? a0 : (r == 1) ? a1 : (r == 2) ? a2 : a3;
    int nn = i * 4 + r;
    int gnn = n0 + nn;
    float sc = scl[nn];
    float4 o = make_float4(leaky(sc * acc.x), leaky(sc * acc.y),
                           leaky(sc * acc.z), leaky(sc * acc.w));
    if (gnn < N) *(float4*)(u + (size_t)gnn * FOUT + fbase) = o;
    buf[nn * 67 + fbase]     = o.x;    // stride 67: read pass conflict-free
    buf[nn * 67 + fbase + 1] = o.y;
    buf[nn * 67 + fbase + 2] = o.z;
    buf[nn * 67 + fbase + 3] = o.w;
  }
  __syncthreads();

  {
    int proj = t >> 6;
    const float* wc = wls + proj * 64;
    int nn = t & 63;
    int gnn = n0 + nn;
    const float* ur = buf + nn * 67;   // (3n+f)%32: conflict-free across lanes
    float acc = 0.f;
#pragma unroll 8
    for (int f = 0; f < 64; ++f) acc = fmaf(ur[f], wc[f], acc);
    if (gnn < N) scl4[(size_t)gnn * 4 + proj] = acc;
  }
}

// ---------------- kernel 2: fused placement + gate (binB (+) aggA) ----------
// Round-10 structure at 512 threads/block (round-12 lesson: the tail is
// latency-bound — TLP is the lever). 4 blocks/CU by LDS AND by threads ->
// ~24 resident waves/CU (vs 12); serial depth halved (4 placement iters,
// 4 gate reps, 4 copy iters).
__global__ __launch_bounds__(512) void k_place(const int2* __restrict__ stg,
                                               const int* __restrict__ bcnt,
                                               const float4* __restrict__ scl4,
                                               int* __restrict__ deg,
                                               int* __restrict__ slots,
                                               float2* __restrict__ gs,
                                               float* __restrict__ tp, int N) {
  __shared__ int slds[128 * MAXDEG];   // 32KB
  __shared__ int cur[128];
  int b = blockIdx.x, t = threadIdx.x;
  if (t < 128) cur[t] = 0;
  __syncthreads();
  int cnt = min(bcnt[b], BKT_CAP);
  int dbase = b << BKT_SHIFT;
  const int2* sp = stg + (size_t)b * BKT_CAP;
  for (int i = t; i < cnt; i += 512) {
    int2 e = sp[i];
    int dl = e.y - dbase;
    int p = atomicAdd(&cur[dl], 1);
    if (p < MAXDEG) slds[dl * MAXDEG + p] = e.x;
  }
  __syncthreads();                 // slds + cur complete

  int nrows = min(128, N - dbase); // rows beyond N must not be written (slots
                                   // is followed by the stg/uw union!)
  if (t < 128 && t < nrows) deg[dbase + t] = min(cur[t], MAXDEG);

  // coalesced slots copy: 2048 int4s, 4 per thread
  {
    int4* gdst = (int4*)(slots + (size_t)dbase * MAXDEG);
    const int4* lsrc = (const int4*)slds;
#pragma unroll
    for (int q = 0; q < 4; ++q) {
      int jj = q * 512 + t;
      if ((jj >> 4) < nrows) gdst[jj] = lsrc[jj];
    }
  }

  // gate phase: 32 groups of 16 lanes; 4 reps cover 128 nodes
  int grp = t >> 4, l16 = t & 15;
#pragma unroll
  for (int rep = 0; rep < 4; ++rep) {
    int nl = rep * 32 + grp;
    int i  = dbase + nl;
    bool act = (i < N);
    int d = act ? min(cur[nl], MAXDEG) : 0;
    float ax = 0.f, ay = 0.f, aw = 0.f;
#pragma unroll
    for (int q = 0; q < 4; ++q) {
      int k = l16 + q * 16;
      if (k < d) {
        int s = slds[nl * MAXDEG + k];
        float4 gg = scl4[s];
        ax += gg.x; ay += gg.y; aw += gg.w;
      }
    }
    ax = red16(ax); ay = red16(ay); aw = red16(aw);
    if (act && l16 == 0) {
      float r0 = fmaxf(ax, 0.f), r1 = fmaxf(ay, 0.f);
      float m  = fmaxf(r0, r1);
      float e0 = expf(r0 - m), e1 = expf(r1 - m);
      float p  = e1 / (e0 + e1);
      float sel = (p > 0.48f) ? 1.f : 0.f;
      float4 own = scl4[i];
      gs[i] = make_float2(sel, sel * own.z);  // {selF, selF*q1}
      tp[i] = aw;                             // sum_neigh . Wlw[64:]
    }
  }
}

// ---------------- kernel 3: weight + in-place compaction + bf16 uw rows -----
// Per node (16 lanes): gather gs[s] for all neighbors (flag = sel, value =
// sel*q1), red16 the sum, ballot-compact the SELECTED srcs back into the
// slots row, write scnt; selected nodes write the bf16 uw row.
__global__ __launch_bounds__(256) void k_wgt(const int* __restrict__ deg,
                                             int* __restrict__ slots,
                                             const float2* __restrict__ gs,
                                             const float* __restrict__ tp,
                                             const float* __restrict__ u,
                                             unsigned int* __restrict__ uw,
                                             int* __restrict__ scnt, int N) {
  if (blockIdx.x == 0 && threadIdx.x < 32)      // zero sentinel row N
    uw[(size_t)N * 32 + threadIdx.x] = 0u;
  int wv = threadIdx.x >> 6, lane = threadIdx.x & 63;
  int g = lane >> 4, l16 = lane & 15;
  int i = blockIdx.x * 16 + wv * 4 + g;
  bool act = (i < N);
  int d = act ? deg[i] : 0;
  int sv[4]; bool f[4];
  float a = 0.f;
#pragma unroll
  for (int q = 0; q < 4; ++q) {
    int k = l16 + q * 16;
    bool valid = k < d;
    int s = 0;
    if (valid) s = slots[(size_t)i * MAXDEG + k];
    sv[q] = s;
    float2 gv = make_float2(0.f, 0.f);
    if (valid) gv = gs[s];
    f[q] = valid && (gv.x != 0.f);
    a += gv.y;
  }
  a = red16(a);                       // all 16 lanes hold sum of gq
  unsigned long long m0 = __ballot(f[0]);
  unsigned long long m1 = __ballot(f[1]);
  unsigned long long m2 = __ballot(f[2]);
  unsigned long long m3 = __ballot(f[3]);
  int sh = g * 16;
  unsigned gm0 = (unsigned)(m0 >> sh) & 0xFFFFu;
  unsigned gm1 = (unsigned)(m1 >> sh) & 0xFFFFu;
  unsigned gm2 = (unsigned)(m2 >> sh) & 0xFFFFu;
  unsigned gm3 = (unsigned)(m3 >> sh) & 0xFFFFu;
  int c0 = __popc(gm0), c1 = __popc(gm1), c2 = __popc(gm2);
  unsigned lm = (1u << l16) - 1u;
  int r0 = __popc(gm0 & lm);
  int r1 = c0 + __popc(gm1 & lm);
  int r2 = c0 + c1 + __popc(gm2 & lm);
  int r3 = c0 + c1 + c2 + __popc(gm3 & lm);
  if (!act) return;
  if (f[0]) slots[(size_t)i * MAXDEG + r0] = sv[0];
  if (f[1]) slots[(size_t)i * MAXDEG + r1] = sv[1];
  if (f[2]) slots[(size_t)i * MAXDEG + r2] = sv[2];
  if (f[3]) slots[(size_t)i * MAXDEG + r3] = sv[3];
  if (l16 == 0) scnt[i] = c0 + c1 + c2 + __popc(gm3);
  if (gs[i].x != 0.f) {               // group-uniform: selected node
    float sig = 1.f / (1.f + expf(-(tp[i] + a)));
    float4 uv = ((const float4*)(u + (size_t)i * 64))[l16];
    unsigned int b0 = bf16rne(sig * uv.x), b1 = bf16rne(sig * uv.y);
    unsigned int b2 = bf16rne(sig * uv.z), b3 = bf16rne(sig * uv.w);
    ((uint2*)(uw + (size_t)i * 32))[l16] =
        make_uint2(b0 | (b1 << 16), b2 | (b3 << 16));
  }
}

// ---------------- kernel 4: vector phase — compacted uw gather --------------
// 16 lanes/node, 16 nodes/block; each lane owns 4 fixed features.
__global__ __launch_bounds__(256) void k_agg3(const int* __restrict__ scnt,
                                              const int* __restrict__ slots,
                                              const uint2* __restrict__ uw,
                                              const float* __restrict__ u,
                                              float* __restrict__ out, int N) {
  __shared__ int comp[16][64];
  int wv = threadIdx.x >> 6, lane = threadIdx.x & 63;
  int g = lane >> 4, l16 = lane & 15;
  int nloc = wv * 4 + g;
  int i = blockIdx.x * 16 + nloc;
  bool act = (i < N);
  int sc = act ? scnt[i] : 0;
#pragma unroll
  for (int b = 0; b < 4; ++b) {
    int idx = b * 16 + l16;
    comp[nloc][idx] = (idx < sc) ? slots[(size_t)i * MAXDEG + idx] : N;
  }
  float4 acc = make_float4(0.f, 0.f, 0.f, 0.f);
  for (int r = 0; r < sc; r += 4) {
#pragma unroll
    for (int j = 0; j < 4; ++j) {
      int s = (r + j < sc) ? comp[nloc][r + j] : N;   // row N is zeroed
      uint2 w = uw[(size_t)s * 16 + l16];
      acc = f4add(acc, bf4(w));
    }
  }
  if (!act) return;
  float4 uv = ((const float4*)(u + (size_t)i * 64))[l16];
  float4 ov = make_float4(uv.x + fmaxf(acc.x, 0.f), uv.y + fmaxf(acc.y, 0.f),
                          uv.z + fmaxf(acc.z, 0.f), uv.w + fmaxf(acc.w, 0.f));
  float ssp = ov.x * ov.x + ov.y * ov.y + ov.z * ov.z + ov.w * ov.w;
  float ss  = red16(ssp);
  float nc  = fmaxf(sqrtf(ss), 1e-15f);
  float th  = tanhf(nc);
  float fac = th / nc;
  float4 r = make_float4(ov.x * fac, ov.y * fac, ov.z * fac, ov.w * fac);
  float n2 = fmaxf(th, 1e-15f);
  float maxn = 1.0f - 4e-3f;
  float sc2 = (n2 > maxn) ? (maxn / n2) : 1.0f;
  float4 res = make_float4(r.x * sc2, r.y * sc2, r.z * sc2, r.w * sc2);
  ((float4*)(out + (size_t)i * 64))[l16] = res;
}

// ---------------- launch ----------------
extern "C" void kernel_launch(void* const* d_in, const int* in_sizes, int n_in,
                              void* d_out, int out_size, void* d_ws, size_t ws_size,
                              hipStream_t stream) {
  const float* x   = (const float*)d_in[0];
  const int*   ei  = (const int*)d_in[1];
  const float* Wup = (const float*)d_in[2];
  const float* Wpl = (const float*)d_in[3];
  const float* Wlw = (const float*)d_in[4];
  float* out = (float*)d_out;

  int N = in_sizes[0] / FIN;     // 100000
  int E = in_sizes[1] / 2;       // 1600000
  int nb = (N + (1 << BKT_SHIFT) - 1) >> BKT_SHIFT;   // 782 buckets

  char* ws = (char*)d_ws;
  float* u     = (float*)ws;                            // 25.6 MB
  int*   slots = (int*)(u + (size_t)N * 64);            // 25.6 MB
  char*  regB  = (char*)(slots + (size_t)N * MAXDEG);   // union: stg | uw
  size_t regB_sz = (size_t)nb * BKT_CAP * sizeof(int2); // 16.0 MB
  int2*  stg   = (int2*)regB;               // lifetime: k_main(binA) -> k_place
  unsigned int* uwp = (unsigned int*)regB;  // lifetime: k_wgt -> agg3
  float* scl4  = (float*)(regB + regB_sz);              // 1.6 MB
  int*   deg   = (int*)(scl4 + (size_t)N * 4);          // 0.4 MB
  float2* gs   = (float2*)(deg + N);                    // 0.8 MB
  float* tp    = (float*)(gs + N);                      // 0.4 MB
  int*   scnt  = (int*)(tp + N);                        // 0.4 MB
  int*   bcnt  = scnt + N;                              // tiny

  (void)hipMemsetAsync(bcnt, 0, nb * sizeof(int), stream);

  int gemmBlocks = (N + 63) / 64;                 // 1563
  int binABlocks = (E + 4095) / 4096;             // 391
  k_main<<<gemmBlocks + binABlocks, 256, 0, stream>>>(
      x, Wup, Wpl, Wlw, u, scl4, ei, E, nb, bcnt, stg, N, gemmBlocks);
  k_place<<<nb, 512, 0, stream>>>(stg, bcnt, (const float4*)scl4, deg, slots, gs, tp, N);
  int nblk16 = (N + 15) / 16;
  k_wgt<<<nblk16, 256, 0, stream>>>(deg, slots, (const float2*)gs, tp, u, uwp, scnt, N);
  k_agg3<<<nblk16, 256, 0, stream>>>(scnt, slots, (const uint2*)uwp, u, out, N);
}